// Round 1
// baseline (1119.273 us; speedup 1.0000x reference)
//
#include <hip/hip_runtime.h>

#define EPS_DENOM 1e-7f
#define EPS_NORM  1e-5f

static constexpr int D = 32;   // feature dim
static constexpr int H = 128;  // hidden dim

// ---------------------------------------------------------------------------
// Kernel 1: per-node FCNNs.  h1 = relu(x@W1a+b1a)@W2a+b2a ; h2 likewise (b).
// One thread per node; weights are wave-uniform -> scalar loads.
// ---------------------------------------------------------------------------
__global__ __launch_bounds__(256) void fcnn_kernel(
    const float* __restrict__ x,
    const float* __restrict__ W1a, const float* __restrict__ b1a,
    const float* __restrict__ W2a, const float* __restrict__ b2a,
    const float* __restrict__ W1b, const float* __restrict__ b1b,
    const float* __restrict__ W2b, const float* __restrict__ b2b,
    float* __restrict__ h1, float* __restrict__ h2, int N)
{
    int n = blockIdx.x * blockDim.x + threadIdx.x;
    if (n >= N) return;

    float xr[D];
    const float4* xv = (const float4*)(x + (size_t)n * D);
    #pragma unroll
    for (int i = 0; i < D / 4; ++i) {
        float4 v = xv[i];
        xr[4*i+0] = v.x; xr[4*i+1] = v.y; xr[4*i+2] = v.z; xr[4*i+3] = v.w;
    }

    float acc1[D], acc2[D];
    #pragma unroll
    for (int d = 0; d < D; ++d) { acc1[d] = b2a[d]; acc2[d] = b2b[d]; }

    #pragma unroll 4
    for (int h = 0; h < H; ++h) {
        float t1 = b1a[h];
        float t2 = b1b[h];
        #pragma unroll
        for (int i = 0; i < D; ++i) {
            t1 = fmaf(xr[i], W1a[i * H + h], t1);   // W1 is [D,H]
            t2 = fmaf(xr[i], W1b[i * H + h], t2);
        }
        t1 = fmaxf(t1, 0.0f);
        t2 = fmaxf(t2, 0.0f);
        #pragma unroll
        for (int d = 0; d < D; ++d) {
            acc1[d] = fmaf(t1, W2a[h * D + d], acc1[d]);   // W2 is [H,D]
            acc2[d] = fmaf(t2, W2b[h * D + d], acc2[d]);
        }
    }

    float4* o1 = (float4*)(h1 + (size_t)n * D);
    float4* o2 = (float4*)(h2 + (size_t)n * D);
    #pragma unroll
    for (int i = 0; i < D / 4; ++i) {
        o1[i] = make_float4(acc1[4*i], acc1[4*i+1], acc1[4*i+2], acc1[4*i+3]);
        o2[i] = make_float4(acc2[4*i], acc2[4*i+1], acc2[4*i+2], acc2[4*i+3]);
    }
}

// ---------------------------------------------------------------------------
// Kernel 2: one pass over edges.  32 lanes per edge (lane = feature d).
//   s = sigmoid(ef[e][d])
//   S1[a][d] += s ;  S1[b][d] += s
//   S2[a][d] += s * h2[b][d] ;  S2[b][d] += s * h2[a][d]
// ---------------------------------------------------------------------------
__global__ __launch_bounds__(256) void edge_kernel(
    const float* __restrict__ ef,
    const int*   __restrict__ ei,   // [2,E]: src row then dst row
    const float* __restrict__ h2,
    float* __restrict__ S1, float* __restrict__ S2, int E)
{
    int t = blockIdx.x * blockDim.x + threadIdx.x;
    int e = t >> 5;
    int d = t & 31;
    if (e >= E) return;

    int a = ei[e];
    int b = ei[E + e];

    float v = ef[(size_t)e * D + d];
    float s = 1.0f / (1.0f + __expf(-v));

    float h2a = h2[(size_t)a * D + d];
    float h2b = h2[(size_t)b * D + d];

    atomicAdd(&S1[(size_t)a * D + d], s);
    atomicAdd(&S1[(size_t)b * D + d], s);
    atomicAdd(&S2[(size_t)a * D + d], s * h2b);
    atomicAdd(&S2[(size_t)b * D + d], s * h2a);
}

// ---------------------------------------------------------------------------
// Kernel 3: finalize.  32 lanes per node.
//   h = h1 + S2/(eps + S1); InstanceNorm over d; out = x + relu(hn)
// ---------------------------------------------------------------------------
__global__ __launch_bounds__(256) void finalize_kernel(
    const float* __restrict__ x,  const float* __restrict__ h1,
    const float* __restrict__ S1, const float* __restrict__ S2,
    float* __restrict__ out, int N)
{
    int t = blockIdx.x * blockDim.x + threadIdx.x;
    int n = t >> 5;
    int d = t & 31;
    if (n >= N) return;

    size_t idx = (size_t)n * D + d;
    float h = h1[idx] + S2[idx] / (EPS_DENOM + S1[idx]);

    float sum = h;
    float sq  = h * h;
    #pragma unroll
    for (int off = 16; off > 0; off >>= 1) {
        sum += __shfl_xor(sum, off, 32);
        sq  += __shfl_xor(sq,  off, 32);
    }
    float mu  = sum * (1.0f / 32.0f);
    float var = fmaxf(sq * (1.0f / 32.0f) - mu * mu, 0.0f);
    float hn  = (h - mu) * rsqrtf(var + EPS_NORM);

    out[idx] = x[idx] + fmaxf(hn, 0.0f);
}

// ---------------------------------------------------------------------------
extern "C" void kernel_launch(void* const* d_in, const int* in_sizes, int n_in,
                              void* d_out, int out_size, void* d_ws, size_t ws_size,
                              hipStream_t stream)
{
    const float* x   = (const float*)d_in[0];
    const float* ef  = (const float*)d_in[1];
    const float* W1a = (const float*)d_in[2];
    const float* b1a = (const float*)d_in[3];
    const float* W2a = (const float*)d_in[4];
    const float* b2a = (const float*)d_in[5];
    const float* W1b = (const float*)d_in[6];
    const float* b1b = (const float*)d_in[7];
    const float* W2b = (const float*)d_in[8];
    const float* b2b = (const float*)d_in[9];
    const int*   ei  = (const int*)d_in[10];
    float* out = (float*)d_out;

    const int N = in_sizes[0] / D;
    const int E = in_sizes[1] / D;

    float* h1 = (float*)d_ws;
    float* h2 = h1 + (size_t)N * D;
    float* S1 = h2 + (size_t)N * D;
    float* S2 = S1 + (size_t)N * D;

    // zero the scatter accumulators (ws is poisoned 0xAA before every launch)
    hipMemsetAsync(S1, 0, (size_t)2 * N * D * sizeof(float), stream);

    fcnn_kernel<<<(N + 255) / 256, 256, 0, stream>>>(
        x, W1a, b1a, W2a, b2a, W1b, b1b, W2b, b2b, h1, h2, N);

    edge_kernel<<<(E + 7) / 8, 256, 0, stream>>>(ef, ei, h2, S1, S2, E);

    finalize_kernel<<<(N + 7) / 8, 256, 0, stream>>>(x, h1, S1, S2, out, N);
}